// Round 6
// baseline (36.471 us; speedup 1.0000x reference)
//
#include <hip/hip_runtime.h>
#include <math.h>

#define BS    8192
#define NCTX  28
#define DM    28

typedef __attribute__((ext_vector_type(8))) short  bfx8;
typedef __attribute__((ext_vector_type(16))) float f32x16;

#define MFMA(A,B,C) __builtin_amdgcn_mfma_f32_32x32x16_bf16((A),(B),(C),0,0,0)

// Split-bf16 weights in MFMA A-fragment order:
//   offset(o,hilo,kt) = o*2048 + hilo*1024 + kt*512  (+ h*256 + c*8 + j) shorts
//   value = W_o[c][k], k = 16*kt + 8*h + j;  k==28 -> bias_o[c];  else-pad 0
__device__ short g_ws[3*2*2*2*32*8];   // 12 KB

__global__ void prep_weights(const float* __restrict__ Wq, const float* __restrict__ bq,
                             const float* __restrict__ Wk, const float* __restrict__ bk,
                             const float* __restrict__ Wv, const float* __restrict__ bv)
{
    for (int i = threadIdx.x; i < 3*32*32; i += blockDim.x) {
        int o = i >> 10, rem = i & 1023, c = rem >> 5, k = rem & 31;
        const float* W  = (o==0) ? Wq : (o==1) ? Wk : Wv;
        const float* bb = (o==0) ? bq : (o==1) ? bk : bv;
        float val = 0.f;
        if (c < 28) { if (k < 28) val = W[c*28 + k]; else if (k == 28) val = bb[c]; }
        unsigned hb = __float_as_uint(val) & 0xFFFF0000u;
        float     r = val - __uint_as_float(hb);
        int kt = k >> 4, hh = (k >> 3) & 1, j = k & 7;
        int idx = o*2048 + kt*512 + hh*256 + c*8 + j;
        g_ws[idx]        = (short)(hb >> 16);                 // hi
        g_ws[idx + 1024] = (short)(__float_as_uint(r) >> 16); // lo
    }
}

// D = A*B + C; A = W (rows=channel c), B = x^T (cols=token m).
// C-layout: col = lane&31 (token), row = (r&3)+8*(r>>2)+4*(lane>>5) (channel).
// Assemble full 28-channel rows per lane via shfl_xor(32) + cndmask; lane
// half h keeps item h. Pure VALU/lgkm, no LDS round-trip, no barriers.
#define QKV_COMPUTE(O, DST)                                                    \
    do {                                                                       \
        bfx8 Wh0 = *(const bfx8*)(g_ws + (O)*2048 +    0 + woff);              \
        bfx8 Wh1 = *(const bfx8*)(g_ws + (O)*2048 +  512 + woff);              \
        bfx8 Wl0 = *(const bfx8*)(g_ws + (O)*2048 + 1024 + woff);              \
        bfx8 Wl1 = *(const bfx8*)(g_ws + (O)*2048 + 1536 + woff);              \
        f32x16 d0, d1;                                                         \
        _Pragma("unroll")                                                      \
        for (int r = 0; r < 16; ++r) { d0[r] = 0.f; d1[r] = 0.f; }             \
        d0 = MFMA(Wh0, Xh[0][0], d0);  d1 = MFMA(Wh0, Xh[1][0], d1);           \
        d0 = MFMA(Wh1, Xh[0][1], d0);  d1 = MFMA(Wh1, Xh[1][1], d1);           \
        d0 = MFMA(Wh0, Xl[0][0], d0);  d1 = MFMA(Wh0, Xl[1][0], d1);           \
        d0 = MFMA(Wh1, Xl[0][1], d0);  d1 = MFMA(Wh1, Xl[1][1], d1);           \
        d0 = MFMA(Wl0, Xh[0][0], d0);  d1 = MFMA(Wl0, Xh[1][0], d1);           \
        d0 = MFMA(Wl1, Xh[0][1], d0);  d1 = MFMA(Wl1, Xh[1][1], d1);           \
        _Pragma("unroll")                                                      \
        for (int r = 0; r < 16; ++r) {                                         \
            float sw0 = __shfl_xor(d0[r], 32, 64);                             \
            float sw1 = __shfl_xor(d1[r], 32, 64);                             \
            const int c0 = (r & 3) + 8*(r >> 2);                               \
            DST[c0] = hsel ? sw1 : d0[r];                                      \
            if (c0 + 4 < DM) DST[c0+4] = hsel ? d1[r] : sw0;                   \
        }                                                                      \
    } while (0)

__global__ __launch_bounds__(256, 4) void l1att_mfma(
    const float* __restrict__ x,
    const float* __restrict__ W1, const float* __restrict__ b1,
    const float* __restrict__ W2, const float* __restrict__ b2,
    float* __restrict__ out)
{
    __shared__ float qs [4][2][NCTX*DM];   // 25088 B, per wave/item
    __shared__ float l1s[4][2][NCTX];
    __shared__ float hs [4][2][20];

    const int tid  = threadIdx.x;
    const int wv   = tid >> 6;
    const int l    = tid & 63;
    const int h    = l >> 5;            // item-half
    const int r31  = l & 31;            // token index
    const int rc   = (r31 < 28) ? r31 : 27;   // clamped row for loads
    const int ib   = blockIdx.x * 8 + wv * 2;
    const bool hsel = (h != 0);

    // ---- x B-fragments, split bf16; k=28 column = 1.0 carries the bias ----
    bfx8 Xh[2][2], Xl[2][2];
    #pragma unroll
    for (int it = 0; it < 2; ++it) {
        const float* rowb = x + ((size_t)(ib + it) * NCTX + rc) * DM;
        #pragma unroll
        for (int kt = 0; kt < 2; ++kt) {
            const int k0 = 16*kt + 8*h;                    // 0,8,16,24 (lane-dep)
            float4 a = *(const float4*)(rowb + k0);
            const float4* p2 = (k0 < 24) ? (const float4*)(rowb + k0 + 4)
                                         : (const float4*)rowb;   // safe dummy
            float4 b4 = *p2;
            if (k0 >= 24) b4 = make_float4(1.f, 0.f, 0.f, 0.f);   // bias column
            float f[8] = {a.x, a.y, a.z, a.w, b4.x, b4.y, b4.z, b4.w};
            bfx8 hi8, lo8;
            #pragma unroll
            for (int j = 0; j < 8; ++j) {
                unsigned xb = __float_as_uint(f[j]);
                unsigned hbits = xb & 0xFFFF0000u;
                float    res = f[j] - __uint_as_float(hbits);
                hi8[j] = (short)(hbits >> 16);
                lo8[j] = (short)(__float_as_uint(res) >> 16);
            }
            Xh[it][kt] = hi8;  Xl[it][kt] = lo8;
        }
    }

    const int woff = h*256 + r31*8;     // lane offset into g_ws (shorts)

    float qr[DM], kr[DM], vr[DM];

    // ---- q: assemble rows in-register, publish per-item q to LDS ----
    QKV_COMPUTE(0, qr);
    if (r31 < 28) {
        float4* qd = (float4*)&qs[wv][h][r31*DM];
        #pragma unroll
        for (int i2 = 0; i2 < 7; ++i2)
            qd[i2] = make_float4(qr[4*i2+0], qr[4*i2+1], qr[4*i2+2], qr[4*i2+3]);
    }

    // ---- k, v: stay in registers ----
    QKV_COMPUTE(1, kr);
    QKV_COMPUTE(2, vr);

    // ---- L1 attention + row-dot with v ----
    if (r31 < 28) {
        const float scale = -0.18898223650461363f;   // -1/sqrt(28)
        const float* qb = &qs[wv][h][0];
        float acc = 0.f;
        #pragma unroll
        for (int j = 0; j < NCTX; ++j) {
            const float4* qj = (const float4*)(qb + j*DM);   // half-uniform broadcast
            float s0=0.f, s1=0.f, s2=0.f, s3=0.f;
            #pragma unroll
            for (int w4 = 0; w4 < 7; ++w4) {
                float4 qv = qj[w4];
                s0 += fabsf(qv.x - kr[4*w4+0]);
                s1 += fabsf(qv.y - kr[4*w4+1]);
                s2 += fabsf(qv.z - kr[4*w4+2]);
                s3 += fabsf(qv.w - kr[4*w4+3]);
            }
            float a = (j == r31) ? 1.0f : scale * ((s0 + s1) + (s2 + s3));
            acc = fmaf(vr[j], a, acc);
        }
        l1s[wv][h][r31] = acc;
    }

    // ---- MLP (wave-private LDS deps, no barriers) ----
    if (r31 < 20) {
        float a = b1[r31];
        #pragma unroll
        for (int w = 0; w < NCTX; ++w) a += l1s[wv][h][w] * W1[r31*NCTX + w];
        hs[wv][h][r31] = fmaxf(a, 0.f);
    }
    if (r31 < 10) {
        float a = b2[r31];
        #pragma unroll
        for (int w = 0; w < 20; ++w) a += hs[wv][h][w] * W2[r31*20 + w];
        out[(size_t)(ib + h)*10 + r31] = a;
    }
}

extern "C" void kernel_launch(void* const* d_in, const int* in_sizes, int n_in,
                              void* d_out, int out_size, void* d_ws, size_t ws_size,
                              hipStream_t stream) {
    const float* x  = (const float*)d_in[0];
    const float* Wq = (const float*)d_in[1];
    const float* bq = (const float*)d_in[2];
    const float* Wk = (const float*)d_in[3];
    const float* bk = (const float*)d_in[4];
    const float* Wv = (const float*)d_in[5];
    const float* bv = (const float*)d_in[6];
    const float* W1 = (const float*)d_in[7];
    const float* b1 = (const float*)d_in[8];
    const float* W2 = (const float*)d_in[9];
    const float* b2 = (const float*)d_in[10];
    float* out = (float*)d_out;

    hipLaunchKernelGGL(prep_weights, dim3(1), dim3(256), 0, stream,
                       Wq, bq, Wk, bk, Wv, bv);

    dim3 grid(BS / 8), block(256);
    hipLaunchKernelGGL(l1att_mfma, grid, block, 0, stream,
                       x, W1, b1, W2, b2, out);
}

// Round 7
// 33.012 us; speedup vs baseline: 1.1048x; 1.1048x over previous
//
#include <hip/hip_runtime.h>
#include <math.h>

#define BS    8192
#define NCTX  28
#define DM    28

typedef __attribute__((ext_vector_type(8))) short  bfx8;
typedef __attribute__((ext_vector_type(16))) float f32x16;

#define MFMA(A,B,C) __builtin_amdgcn_mfma_f32_32x32x16_bf16((A),(B),(C),0,0,0)

// Split-bf16 weights in MFMA B-fragment order (B[k][n] = W[n][k], bias at k=28):
//   idx(o,hilo,kt,h,n,j) = o*2048 + hilo*1024 + kt*512 + h*256 + n*8 + j  (shorts)
//   k = 16*kt + 8*h + j;  n>=28 or k>28 -> 0
__device__ short g_ws[3 * 2048];   // 12 KB

__global__ void prep_weights(const float* __restrict__ Wq, const float* __restrict__ bq,
                             const float* __restrict__ Wk, const float* __restrict__ bk,
                             const float* __restrict__ Wv, const float* __restrict__ bv)
{
    for (int i = threadIdx.x; i < 3*32*32; i += blockDim.x) {
        int o = i >> 10, rem = i & 1023, c = rem >> 5, k = rem & 31;
        const float* W  = (o==0) ? Wq : (o==1) ? Wk : Wv;
        const float* bb = (o==0) ? bq : (o==1) ? bk : bv;
        float val = 0.f;
        if (c < 28) { if (k < 28) val = W[c*28 + k]; else if (k == 28) val = bb[c]; }
        unsigned hb = __float_as_uint(val) & 0xFFFF0000u;
        float     r = val - __uint_as_float(hb);
        int kt = k >> 4, hh = (k >> 3) & 1, j = k & 7;
        int idx = o*2048 + kt*512 + hh*256 + c*8 + j;
        g_ws[idx]        = (short)(hb >> 16);                 // hi
        g_ws[idx + 1024] = (short)(__float_as_uint(r) >> 16); // lo
    }
}

// One wave = 2 items, whole kernel barrier-free (wave-private LDS regions).
__global__ __launch_bounds__(256, 4) void l1att_mfma(
    const float* __restrict__ x,
    const float* __restrict__ W1, const float* __restrict__ b1,
    const float* __restrict__ W2, const float* __restrict__ b2,
    float* __restrict__ out)
{
    __shared__ float qs [4][2][NCTX*DM];  // persistent q rows, per wave/item
    __shared__ float scr[4][NCTX*DM];     // k/v transpose scratch, per wave
    __shared__ float l1s[4][2][NCTX];
    __shared__ float hs [4][2][20];

    const int tid = threadIdx.x;
    const int wv  = tid >> 6;        // wave in block
    const int l   = tid & 63;        // lane
    const int h   = l >> 5;          // k-group for frags == item-half later
    const int r31 = l & 31;          // row/col within 32-tile == row m later
    const int rc  = (r31 < 28) ? r31 : 0;   // clamped (pad rows -> junk, unread)
    const int ib  = blockIdx.x * 8 + wv * 2;  // first item of this wave

    // ---------- A fragments: x rows, split bf16; 1.0 at k=28 carries bias ----------
    // mfma_32x32x16 A-layout: lane holds A[row=l&31][k = 16*kt + 8*(l>>5) + j]
    bfx8 Ah[2][2], Al[2][2];
    #pragma unroll
    for (int it = 0; it < 2; ++it) {
        const float* rowb = x + ((size_t)(ib + it) * NCTX + rc) * DM;
        #pragma unroll
        for (int kt = 0; kt < 2; ++kt) {
            const int k0 = 16*kt + 8*h;          // 0,8,16,24
            float4 a = *(const float4*)(rowb + k0);
            float4 b4;
            if (k0 < 24) b4 = *(const float4*)(rowb + k0 + 4);
            else         b4 = make_float4(1.f, 0.f, 0.f, 0.f);   // k=28 bias column
            float f[8] = {a.x, a.y, a.z, a.w, b4.x, b4.y, b4.z, b4.w};
            bfx8 hi8, lo8;
            #pragma unroll
            for (int j = 0; j < 8; ++j) {
                unsigned xb = __float_as_uint(f[j]);
                unsigned hbits = xb & 0xFFFF0000u;
                float    res = f[j] - __uint_as_float(hbits);
                hi8[j] = (short)(hbits >> 16);
                lo8[j] = (short)(__float_as_uint(res) >> 16);
            }
            Ah[it][kt] = hi8;  Al[it][kt] = lo8;
        }
    }

    const int woff = h*256 + r31*8;   // lane offset into g_ws fragment table

    float kr[DM], vr[DM];

    // ---------------- q (written to persistent LDS, C-layout -> [m][c]) -------------
    {
        const short* wp = g_ws + 0*2048 + woff;
        bfx8 Bh0 = *(const bfx8*)(wp);
        bfx8 Bh1 = *(const bfx8*)(wp + 512);
        bfx8 Bl0 = *(const bfx8*)(wp + 1024);
        bfx8 Bl1 = *(const bfx8*)(wp + 1536);
        #pragma unroll
        for (int it = 0; it < 2; ++it) {
            f32x16 acc;
            #pragma unroll
            for (int r = 0; r < 16; ++r) acc[r] = 0.f;
            acc = MFMA(Ah[it][0], Bh0, acc);
            acc = MFMA(Ah[it][1], Bh1, acc);
            acc = MFMA(Ah[it][0], Bl0, acc);
            acc = MFMA(Ah[it][1], Bl1, acc);
            acc = MFMA(Al[it][0], Bh0, acc);
            acc = MFMA(Al[it][1], Bh1, acc);
            if (r31 < 28) {
                #pragma unroll
                for (int r = 0; r < 16; ++r) {
                    int row = (r & 3) + 8*(r >> 2) + 4*h;
                    if (row < 28) qs[wv][it][row*DM + r31] = acc[r];
                }
            }
        }
    }

    // ---------------- k (scratch round-trip -> kr registers) ----------------
    {
        const short* wp = g_ws + 1*2048 + woff;
        bfx8 Bh0 = *(const bfx8*)(wp);
        bfx8 Bh1 = *(const bfx8*)(wp + 512);
        bfx8 Bl0 = *(const bfx8*)(wp + 1024);
        bfx8 Bl1 = *(const bfx8*)(wp + 1536);
        #pragma unroll
        for (int it = 0; it < 2; ++it) {
            f32x16 acc;
            #pragma unroll
            for (int r = 0; r < 16; ++r) acc[r] = 0.f;
            acc = MFMA(Ah[it][0], Bh0, acc);
            acc = MFMA(Ah[it][1], Bh1, acc);
            acc = MFMA(Ah[it][0], Bl0, acc);
            acc = MFMA(Ah[it][1], Bl1, acc);
            acc = MFMA(Al[it][0], Bh0, acc);
            acc = MFMA(Al[it][1], Bh1, acc);
            if (r31 < 28) {
                #pragma unroll
                for (int r = 0; r < 16; ++r) {
                    int row = (r & 3) + 8*(r >> 2) + 4*h;
                    if (row < 28) scr[wv][row*DM + r31] = acc[r];
                }
            }
            // lanes of half `it` read their row back before next it overwrites
            // (in-order DS pipe per wave -> no barrier needed)
            if (h == it && r31 < 28) {
                const float4* kp = (const float4*)&scr[wv][r31*DM];
                #pragma unroll
                for (int i = 0; i < 7; ++i) {
                    float4 t = kp[i];
                    kr[4*i+0]=t.x; kr[4*i+1]=t.y; kr[4*i+2]=t.z; kr[4*i+3]=t.w;
                }
            }
        }
    }

    // ---------------- v (same pattern -> vr registers) ----------------
    {
        const short* wp = g_ws + 2*2048 + woff;
        bfx8 Bh0 = *(const bfx8*)(wp);
        bfx8 Bh1 = *(const bfx8*)(wp + 512);
        bfx8 Bl0 = *(const bfx8*)(wp + 1024);
        bfx8 Bl1 = *(const bfx8*)(wp + 1536);
        #pragma unroll
        for (int it = 0; it < 2; ++it) {
            f32x16 acc;
            #pragma unroll
            for (int r = 0; r < 16; ++r) acc[r] = 0.f;
            acc = MFMA(Ah[it][0], Bh0, acc);
            acc = MFMA(Ah[it][1], Bh1, acc);
            acc = MFMA(Ah[it][0], Bl0, acc);
            acc = MFMA(Ah[it][1], Bl1, acc);
            acc = MFMA(Al[it][0], Bh0, acc);
            acc = MFMA(Al[it][1], Bh1, acc);
            if (r31 < 28) {
                #pragma unroll
                for (int r = 0; r < 16; ++r) {
                    int row = (r & 3) + 8*(r >> 2) + 4*h;
                    if (row < 28) scr[wv][row*DM + r31] = acc[r];
                }
            }
            if (h == it && r31 < 28) {
                const float4* vp = (const float4*)&scr[wv][r31*DM];
                #pragma unroll
                for (int i = 0; i < 7; ++i) {
                    float4 t = vp[i];
                    vr[4*i+0]=t.x; vr[4*i+1]=t.y; vr[4*i+2]=t.z; vr[4*i+3]=t.w;
                }
            }
        }
    }

    // ---------------- L1 attention + row-dot with v ----------------
    if (r31 < 28) {
        const float scale = -0.18898223650461363f;   // -1/sqrt(28)
        const float* qb = &qs[wv][h][0];
        float acc = 0.f;
        #pragma unroll
        for (int j = 0; j < NCTX; ++j) {
            const float4* qj = (const float4*)(qb + j*DM);  // half-uniform broadcast
            float s0=0.f, s1=0.f, s2=0.f, s3=0.f;
            #pragma unroll
            for (int w4 = 0; w4 < 7; ++w4) {
                float4 qv = qj[w4];
                s0 += fabsf(qv.x - kr[4*w4+0]);
                s1 += fabsf(qv.y - kr[4*w4+1]);
                s2 += fabsf(qv.z - kr[4*w4+2]);
                s3 += fabsf(qv.w - kr[4*w4+3]);
            }
            float a = (j == r31) ? 1.0f : scale * ((s0 + s1) + (s2 + s3));
            acc = fmaf(vr[j], a, acc);
        }
        l1s[wv][h][r31] = acc;
    }

    // ---------------- MLP (same-wave LDS deps, no barrier) ----------------
    if (r31 < 20) {
        float a = b1[r31];
        #pragma unroll
        for (int w = 0; w < NCTX; ++w) a += l1s[wv][h][w] * W1[r31*NCTX + w];
        hs[wv][h][r31] = fmaxf(a, 0.f);
    }
    if (r31 < 10) {
        float a = b2[r31];
        #pragma unroll
        for (int w = 0; w < 20; ++w) a += hs[wv][h][w] * W2[r31*20 + w];
        out[(size_t)(ib + h)*10 + r31] = a;
    }
}

extern "C" void kernel_launch(void* const* d_in, const int* in_sizes, int n_in,
                              void* d_out, int out_size, void* d_ws, size_t ws_size,
                              hipStream_t stream) {
    const float* x  = (const float*)d_in[0];
    const float* Wq = (const float*)d_in[1];
    const float* bq = (const float*)d_in[2];
    const float* Wk = (const float*)d_in[3];
    const float* bk = (const float*)d_in[4];
    const float* Wv = (const float*)d_in[5];
    const float* bv = (const float*)d_in[6];
    const float* W1 = (const float*)d_in[7];
    const float* b1 = (const float*)d_in[8];
    const float* W2 = (const float*)d_in[9];
    const float* b2 = (const float*)d_in[10];
    float* out = (float*)d_out;

    hipLaunchKernelGGL(prep_weights, dim3(1), dim3(256), 0, stream,
                       Wq, bq, Wk, bk, Wv, bv);

    dim3 grid(BS / 8), block(256);
    hipLaunchKernelGGL(l1att_mfma, grid, block, 0, stream,
                       x, W1, b1, W2, b2, out);
}

// Round 8
// 24.039 us; speedup vs baseline: 1.5171x; 1.3732x over previous
//
#include <hip/hip_runtime.h>
#include <math.h>

#define BS    8192
#define NCTX  28
#define DM    28

typedef __attribute__((ext_vector_type(8))) short  bfx8;
typedef __attribute__((ext_vector_type(16))) float f32x16;

#define MFMA(A,B,C) __builtin_amdgcn_mfma_f32_32x32x16_bf16((A),(B),(C),0,0,0)

// Load 8 consecutive floats of a 28-float row, split each into bf16-hi + bf16-lo.
// k0==24 -> last 4 lanes of K are {tail,0,0,0}: the k=28 "bias column" slot.
__device__ __forceinline__ void load8_cvt(const float* rowbase, int k0, float tail,
                                          bfx8& hi, bfx8& lo)
{
    float4 a = *(const float4*)(rowbase + k0);
    float4 b4;
    if (k0 < 24) b4 = *(const float4*)(rowbase + k0 + 4);
    else         b4 = make_float4(tail, 0.f, 0.f, 0.f);
    float f[8] = {a.x, a.y, a.z, a.w, b4.x, b4.y, b4.z, b4.w};
    #pragma unroll
    for (int j = 0; j < 8; ++j) {
        unsigned xb = __float_as_uint(f[j]);
        unsigned hb = xb & 0xFFFF0000u;
        float    r  = f[j] - __uint_as_float(hb);
        hi[j] = (short)(hb >> 16);
        lo[j] = (short)(__float_as_uint(r) >> 16);
    }
}

// D = W * x^T  (A=W rows=channels, B=x^T cols=tokens).
// C-layout (m74/m101): col = lane&31 = token, row = (r&3)+8*(r>>2)+4*(lane>>5) = channel.
// One v_permlane32_swap_b32 per reg pair leaves, in EVERY lane (its own item/token):
//   d0[r] -> channel (r&3)+8*(r>>2)      (even 4-blocks)
//   d1[r] -> channel (r&3)+8*(r>>2) + 4  (odd 4-blocks; r>=12 -> ch>=28 junk, skipped)
// Zero LDS, zero cndmask: the k/v transpose round-trip is gone.
#define QKV_OP(Wmat, bvec, DST)                                               \
    do {                                                                      \
        float tail = (bvec)[rc];                                              \
        bfx8 Wh0, Wl0, Wh1, Wl1;                                              \
        load8_cvt((Wmat) + rc*DM, 8*h,      0.f,  Wh0, Wl0);                  \
        load8_cvt((Wmat) + rc*DM, 16 + 8*h, tail, Wh1, Wl1);                  \
        f32x16 d0, d1;                                                        \
        _Pragma("unroll")                                                     \
        for (int r = 0; r < 16; ++r) { d0[r] = 0.f; d1[r] = 0.f; }            \
        d0 = MFMA(Wh0, Xh[0][0], d0);  d1 = MFMA(Wh0, Xh[1][0], d1);          \
        d0 = MFMA(Wh1, Xh[0][1], d0);  d1 = MFMA(Wh1, Xh[1][1], d1);          \
        d0 = MFMA(Wh0, Xl[0][0], d0);  d1 = MFMA(Wh0, Xl[1][0], d1);          \
        d0 = MFMA(Wh1, Xl[0][1], d0);  d1 = MFMA(Wh1, Xl[1][1], d1);          \
        d0 = MFMA(Wl0, Xh[0][0], d0);  d1 = MFMA(Wl0, Xh[1][0], d1);          \
        d0 = MFMA(Wl1, Xh[0][1], d0);  d1 = MFMA(Wl1, Xh[1][1], d1);          \
        _Pragma("unroll")                                                     \
        for (int r = 0; r < 16; ++r) {                                        \
            float ea = d0[r], ob = d1[r];                                     \
            asm("v_permlane32_swap_b32 %0, %1" : "+v"(ea), "+v"(ob));         \
            const int c0 = (r & 3) + 8*(r >> 2);                              \
            DST[c0] = ea;                                                     \
            if (c0 + 4 < DM) DST[c0 + 4] = ob;                                \
        }                                                                     \
    } while (0)

// One wave = 2 items (lane-half h = item), whole kernel barrier-free.
__global__ __launch_bounds__(256, 4) void l1att_mfma(
    const float* __restrict__ x,
    const float* __restrict__ Wq, const float* __restrict__ bq,
    const float* __restrict__ Wk, const float* __restrict__ bk,
    const float* __restrict__ Wv, const float* __restrict__ bv,
    const float* __restrict__ W1, const float* __restrict__ b1,
    const float* __restrict__ W2, const float* __restrict__ b2,
    float* __restrict__ out)
{
    __shared__ float qs [4][2][NCTX*DM];   // 25088 B: q rows per wave/item
    __shared__ float l1s[4][2][NCTX];
    __shared__ float hs [4][2][20];

    const int tid = threadIdx.x;
    const int wv  = tid >> 6;
    const int l   = tid & 63;
    const int h   = l >> 5;                 // k-subgroup for frags == item index
    const int r31 = l & 31;                 // token (and W-channel row for A-frags)
    const int rc  = (r31 < 28) ? r31 : 0;   // clamp: junk rows/cols never read back
    const int ib  = blockIdx.x * 8 + wv * 2;

    // ---- x fragments (B-operand): lane r31 = token, k = 16*kt + 8*h + j ----
    // k=28 slot = 1.0 -> bias column multiplies W's k=28 slot = bias value.
    bfx8 Xh[2][2], Xl[2][2];
    #pragma unroll
    for (int it = 0; it < 2; ++it) {
        const float* rowb = x + ((size_t)(ib + it) * NCTX + rc) * DM;
        load8_cvt(rowb, 8*h,      1.f, Xh[it][0], Xl[it][0]);
        load8_cvt(rowb, 16 + 8*h, 1.f, Xh[it][1], Xl[it][1]);
    }

    float qr[DM], kr[DM], vr[DM];

    // ---- q: canonical row in regs -> 7 clean b128 LDS writes (own half-region) ----
    QKV_OP(Wq, bq, qr);
    if (r31 < 28) {
        float4* qd = (float4*)&qs[wv][h][r31*DM];
        #pragma unroll
        for (int g = 0; g < 7; ++g)
            qd[g] = make_float4(qr[4*g+0], qr[4*g+1], qr[4*g+2], qr[4*g+3]);
    }

    // ---- k, v: stay entirely in registers ----
    QKV_OP(Wk, bk, kr);
    QKV_OP(Wv, bv, vr);

    // ---- L1 attention + row-dot with v ----
    if (r31 < 28) {
        const float scale = -0.18898223650461363f;   // -1/sqrt(28)
        const float* qb = &qs[wv][h][0];
        float acc = 0.f;
        #pragma unroll
        for (int j = 0; j < NCTX; ++j) {
            const float4* qj = (const float4*)(qb + j*DM);   // half-uniform broadcast
            float s0=0.f, s1=0.f, s2=0.f, s3=0.f;
            #pragma unroll
            for (int w4 = 0; w4 < 7; ++w4) {
                float4 qv = qj[w4];
                s0 += fabsf(qv.x - kr[4*w4+0]);
                s1 += fabsf(qv.y - kr[4*w4+1]);
                s2 += fabsf(qv.z - kr[4*w4+2]);
                s3 += fabsf(qv.w - kr[4*w4+3]);
            }
            float a = (j == r31) ? 1.0f : scale * ((s0 + s1) + (s2 + s3));
            acc = fmaf(vr[j], a, acc);
        }
        l1s[wv][h][r31] = acc;
    }

    // ---- MLP (wave-private LDS deps, in-order DS pipe -> no barrier) ----
    if (r31 < 20) {
        float a = b1[r31];
        #pragma unroll
        for (int w = 0; w < NCTX; ++w) a += l1s[wv][h][w] * W1[r31*NCTX + w];
        hs[wv][h][r31] = fmaxf(a, 0.f);
    }
    if (r31 < 10) {
        float a = b2[r31];
        #pragma unroll
        for (int w = 0; w < 20; ++w) a += hs[wv][h][w] * W2[r31*20 + w];
        out[(size_t)(ib + h)*10 + r31] = a;
    }
}

extern "C" void kernel_launch(void* const* d_in, const int* in_sizes, int n_in,
                              void* d_out, int out_size, void* d_ws, size_t ws_size,
                              hipStream_t stream) {
    const float* x  = (const float*)d_in[0];
    const float* Wq = (const float*)d_in[1];
    const float* bq = (const float*)d_in[2];
    const float* Wk = (const float*)d_in[3];
    const float* bk = (const float*)d_in[4];
    const float* Wv = (const float*)d_in[5];
    const float* bv = (const float*)d_in[6];
    const float* W1 = (const float*)d_in[7];
    const float* b1 = (const float*)d_in[8];
    const float* W2 = (const float*)d_in[9];
    const float* b2 = (const float*)d_in[10];
    float* out = (float*)d_out;

    dim3 grid(BS / 8), block(256);
    hipLaunchKernelGGL(l1att_mfma, grid, block, 0, stream,
                       x, Wq, bq, Wk, bk, Wv, bv, W1, b1, W2, b2, out);
}